// Round 13
// baseline (312.927 us; speedup 1.0000x reference)
//
#include <hip/hip_runtime.h>
#include <hip/hip_bf16.h>

// Problem constants
#define B_  8
#define C_  256
#define H_  96
#define W_  96
#define G_  8
#define CPG 32          // C_/G_
#define KK  9           // 3x3 taps
#define O_  72          // G_*KK conv out channels
#define HW  9216        // H_*W_
#define NPX 73728       // B_*HW (BN population per channel)

typedef short bf16x8 __attribute__((ext_vector_type(8)));
typedef float f32x4 __attribute__((ext_vector_type(4)));

__device__ __forceinline__ unsigned short f2bf(float f) {    // fp32 -> bf16 RNE
    union { float f; unsigned u; } v; v.f = f;
    unsigned r = v.u + 0x7fffu + ((v.u >> 16) & 1u);
    return (unsigned short)(r >> 16);
}
__device__ __forceinline__ float bf2f(unsigned short h) {
    union { float f; unsigned u; } v; v.u = ((unsigned)h) << 16;
    return v.f;
}

// ---------------- K0: weight prepack, per-(tap,chunk) CONTIGUOUS 10KB blocks ----------------
// tix2 = tap*8 + cblk (cblk = kh*4+ch). Within block: offset = (p*5+nt)*512 + l*8 + j.
__global__ __launch_bounds__(256) void bprep_kernel(const float* __restrict__ w,
                                                    unsigned short* __restrict__ bpk) {
    int idx = blockIdx.x * 256 + threadIdx.x;        // 72*5120 = 368640
    if (idx >= 368640) return;
    int tix2 = idx / 5120;
    int r = idx - tix2 * 5120;
    int fi = r >> 9;                 // p*5+nt, 0..9
    int p = fi / 5, nt = fi - p * 5;
    int li = r & 511;
    int l = li >> 3, j = li & 7;
    int tap = tix2 >> 3, cblk = tix2 & 7;
    int o = nt * 16 + (l & 15);
    int c = cblk * 32 + ((l >> 4) << 3) + j;
    unsigned short val = 0;
    if (o < O_) {
        float wv = w[((size_t)o * C_ + c) * KK + tap];
        unsigned short h = f2bf(wv);
        val = (p == 0) ? h : f2bf(wv - bf2f(h));
    }
    bpk[idx] = val;
}

// ---------------- K2: xn = sum_ch xg*gapsum, scale 1/HW, + per-(b,g) sum/sumsq ----------------
__global__ __launch_bounds__(256) void xn_kernel(const float* __restrict__ x,
                                                 const float* __restrict__ gap,
                                                 float* __restrict__ xng,
                                                 float* __restrict__ sge_stats) {
    int blk = blockIdx.x;                    // B_*G_*36 = 2304
    int bg = blk / 36, chunk = blk % 36;
    int b = bg >> 3, g = bg & 7;
    int p = chunk * 256 + threadIdx.x;
    const float* xbase = x + ((size_t)b * C_ + g * CPG) * HW + p;
    const float* gp = gap + b * C_ + g * CPG;
    float v = 0.f;
    #pragma unroll
    for (int ch = 0; ch < CPG; ch++) v += xbase[(size_t)ch * HW] * gp[ch];
    v *= (1.f / (float)HW);
    xng[(size_t)bg * HW + p] = v;
    float v1 = v, v2 = v * v;
    #pragma unroll
    for (int m = 32; m >= 1; m >>= 1) {
        v1 += __shfl_xor(v1, m, 64);
        v2 += __shfl_xor(v2, m, 64);
    }
    __shared__ float r1[4], r2[4];
    int wid = threadIdx.x >> 6;
    if ((threadIdx.x & 63) == 0) { r1[wid] = v1; r2[wid] = v2; }
    __syncthreads();
    if (threadIdx.x == 0) {
        atomicAdd(&sge_stats[bg * 2 + 0], r1[0] + r1[1] + r1[2] + r1[3]);
        atomicAdd(&sge_stats[bg * 2 + 1], r2[0] + r2[1] + r2[2] + r2[3]);
    }
}

// ---------------- K4: implicit-GEMM MFMA conv, REGISTER B panels, barrier-light ----------------
// v14: R12's conv was NOT LDS-throughput bound (MFMA 1746cy vs LDS 1536cy per tap-round,
// but wall ~4800cy): the 36 per-tap barriers (each with compiler vmcnt/lgkm drain for the
// B LDS publish) convoyed 8 barrier-locked waves at 2 blocks/CU. Fix: B panel lives in
// REGISTERS per wave (10x bf16x8 = 40 VGPR; 2 panels, parity rotation, 2-tap-ahead
// prefetch from global — coalesced 1KB steps, panels L2-resident). Barriers 36 -> 8
// (x-staging only). 2-chunk-unrolled loop keeps panel parity compile-time (9 odd).
#define STAGE_LOAD(CH) do {                                                      \
    const float* p0_ = sb0 + (size_t)(CH) * 32 * HW;                             \
    const float* p1_ = p0_ + HW;                                                 \
    _Pragma("unroll")                                                            \
    for (int m2 = 0; m2 < 6; m2++) {                                             \
        a0[m2] = *(const f32x4*)(p0_ + 4 * m2);                                  \
        a1[m2] = *(const f32x4*)(p1_ + 4 * m2);                                  \
    }                                                                            \
} while (0)

#define PACK_HL(F0, F1, HI, LO) do {                                             \
    unsigned b0_ = __builtin_bit_cast(unsigned, (F0));                           \
    unsigned b1_ = __builtin_bit_cast(unsigned, (F1));                           \
    HI = __builtin_amdgcn_perm(b1_, b0_, 0x07060302u);                           \
    float h0_ = __builtin_bit_cast(float, b0_ & 0xffff0000u);                    \
    float h1_ = __builtin_bit_cast(float, b1_ & 0xffff0000u);                    \
    LO = __builtin_amdgcn_perm(__builtin_bit_cast(unsigned, (F1) - h1_),         \
                               __builtin_bit_cast(unsigned, (F0) - h0_),         \
                               0x07060302u);                                     \
} while (0)

#define STAGE_WRITE(CH) do {                                                     \
    _Pragma("unroll")                                                            \
    for (int m2 = 0; m2 < 6; m2++)                                               \
        _Pragma("unroll")                                                        \
        for (int e = 0; e < 4; e++) {                                            \
            int col = sq * 24 + 1 + m2 * 4 + e;                                  \
            unsigned hi_, lo_;                                                   \
            PACK_HL(a0[m2][e], a1[m2][e], hi_, lo_);                             \
            int row = (rbase + col) ^ par;                                       \
            int off = row * 16 + ((spHi ^ ((col >> 1) & 3)) << 2) + spLo;        \
            xsH[off] = hi_; xsL[off] = lo_;                                      \
        }                                                                        \
    if (sq == 0 || sq == 3) {                                                    \
        float f0_ = (sq == 0) ? a0[0][1] : a0[5][2];                             \
        float f1_ = (sq == 0) ? a1[0][1] : a1[5][2];                             \
        int col = (sq == 0) ? 0 : 97;                                            \
        unsigned hi_, lo_;                                                       \
        PACK_HL(f0_, f1_, hi_, lo_);                                             \
        int row = (rbase + col) ^ par;                                           \
        int off = row * 16 + ((spHi ^ ((col >> 1) & 3)) << 2) + spLo;            \
        xsH[off] = hi_; xsL[off] = lo_;                                          \
    }                                                                            \
    {   /* gap: owned rows srr 1,2 (all lanes run the shuffle) */                \
        float s0_ = 0.f, s1_ = 0.f;                                              \
        if (srr == 1 || srr == 2) {                                              \
            _Pragma("unroll")                                                    \
            for (int m2 = 0; m2 < 6; m2++) {                                     \
                s0_ += a0[m2][0] + a0[m2][1] + a0[m2][2] + a0[m2][3];            \
                s1_ += a1[m2][0] + a1[m2][1] + a1[m2][2] + a1[m2][3];            \
            }                                                                    \
        }                                                                        \
        s0_ += __shfl_xor(s0_, 48, 64);                                          \
        s1_ += __shfl_xor(s1_, 48, 64);                                          \
        if (srr == 1) {                                                          \
            gapP[(CH) * 128 + sq * 32 + 2 * sp]     = s0_;                       \
            gapP[(CH) * 128 + sq * 32 + 2 * sp + 1] = s1_;                       \
        }                                                                        \
    }                                                                            \
} while (0)

// load B panel for k-step TIX2 into register panel P (10 x bf16x8)
#define BLOAD(P, TIX2) do {                                                      \
    const unsigned short* bp_ = bpk + (size_t)(TIX2) * 5120 + (l << 3);          \
    _Pragma("unroll")                                                            \
    for (int q = 0; q < 10; q++) P[q] = *(const bf16x8*)(bp_ + q * 512);         \
} while (0)

// one tap: A frags from LDS, 45 MFMA from panel P, then prefetch tap+2 into P.
// chv is the runtime chunk index; TAP is a literal 0..8.
#define TAPB(TAP, P) do {                                                        \
    int rr_ = rw + (TAP) / 3;                                                    \
    int rpar_ = rr_ & 1, rb_ = rr_ * 98;                                         \
    int cs_ = ((colb + (TAP) % 3) >> 1) & 3;                                     \
    int sl_ = (lg ^ cs_) << 2;                                                   \
    bf16x8 ah[3], al[3];                                                         \
    _Pragma("unroll")                                                            \
    for (int m = 0; m < 3; m++) {                                                \
        int row = (rb_ + colb + m * 16 + (TAP) % 3) ^ rpar_;                     \
        ah[m] = *(const bf16x8*)&xsH[row * 16 + sl_];                            \
        al[m] = *(const bf16x8*)&xsL[row * 16 + sl_];                            \
    }                                                                            \
    if ((TAP) == 7 && chv < 3) STAGE_LOAD(chv + 1);                              \
    _Pragma("unroll")                                                            \
    for (int m = 0; m < 3; m++)                                                  \
        _Pragma("unroll")                                                        \
        for (int nt = 0; nt < 5; nt++) {                                         \
            acc[m][nt] = __builtin_amdgcn_mfma_f32_16x16x32_bf16(ah[m], P[nt],     acc[m][nt], 0, 0, 0); \
            acc[m][nt] = __builtin_amdgcn_mfma_f32_16x16x32_bf16(ah[m], P[5 + nt], acc[m][nt], 0, 0, 0); \
            acc[m][nt] = __builtin_amdgcn_mfma_f32_16x16x32_bf16(al[m], P[nt],     acc[m][nt], 0, 0, 0); \
        }                                                                        \
    if (chv * 9 + (TAP) <= 33) {          /* prefetch g+2 (same parity -> P) */  \
        int tp2_ = ((TAP) < 7) ? (TAP) + 2 : (TAP) - 7;                          \
        int ch2_ = ((TAP) < 7) ? chv : chv + 1;                                  \
        BLOAD(P, tp2_ * 8 + khb + ch2_);                                         \
    }                                                                            \
} while (0)

__global__ __launch_bounds__(256, 2) void conv_kernel(const float* __restrict__ x,
                                                      const unsigned short* __restrict__ bpk,
                                                      float* __restrict__ sA,
                                                      float* __restrict__ sB,
                                                      float* __restrict__ gap) {
    __shared__ unsigned xsH[4 * 98 * 16];        // 25088 B
    __shared__ unsigned xsL[4 * 98 * 16];        // 25088 B
    __shared__ float gapP[512];                  // [chunk][wave][cc] single-writer slots
    int phys = blockIdx.x;                       // 768
    int blk = (phys & 7) * 96 + (phys >> 3);     // bijective XCD chunking
    int kh = blk & 1;                            // channel half
    int np = blk >> 1;                           // 0..383
    int n = np / 48, pair = np % 48;
    int i0 = pair * 2;
    int t = threadIdx.x;
    int l = t & 63, wave = t >> 6;
    int rw = wave & 1, mh = wave >> 1;
    int l15 = l & 15, lg = l >> 4;
    int colb = mh * 48 + l15;
    int khb = kh * 4;
    const float* xb = x + (size_t)n * C_ * HW + (size_t)kh * 128 * HW;
    float* sOut = kh ? sB : sA;

    // staging decomposition: sp = ccpair, srr = row, sq = col quarter (== wave)
    int sp = t & 15, srr = (t >> 4) & 3, sq = wave;
    int sri = i0 - 1 + srr;
    if (sri < 0) sri = 1; else if (sri > 95) sri = 94;
    const float* sb0 = xb + (size_t)(2 * sp) * HW + sri * W_ + sq * 24;
    int spHi = sp >> 2, spLo = sp & 3;
    int rbase = srr * 98, par = srr & 1;

    f32x4 acc[3][5];
    #pragma unroll
    for (int m = 0; m < 3; m++)
        #pragma unroll
        for (int nt = 0; nt < 5; nt++)
            #pragma unroll
            for (int e = 0; e < 4; e++) acc[m][nt][e] = 0.f;

    f32x4 a0[6], a1[6];
    bf16x8 bA[10], bB[10];                       // two register B panels (parity rotation)

    // ---- prologue: x chunk 0 -> xs; B panels for g=0 (->bA) and g=1 (->bB) ----
    {
        STAGE_LOAD(0);
        STAGE_WRITE(0);
        BLOAD(bA, khb);                          // g=0: tap0, ch0
        BLOAD(bB, 8 + khb);                      // g=1: tap1, ch0
    }
    __syncthreads();

    #pragma unroll 1
    for (int chp = 0; chp < 2; chp++) {
        {   // even chunk (g starts even -> taps use A,B,A,B,A,B,A,B,A)
            int chv = chp * 2;
            TAPB(0, bA); TAPB(1, bB); TAPB(2, bA); TAPB(3, bB); TAPB(4, bA);
            TAPB(5, bB); TAPB(6, bA); TAPB(7, bB); TAPB(8, bA);
            __syncthreads();                     // xs reads done
            STAGE_WRITE(chv + 1);                // chv in {0,2} -> always < 3
            __syncthreads();                     // xs writes visible
        }
        {   // odd chunk (g starts odd -> taps use B,A,B,A,B,A,B,A,B)
            int chv = chp * 2 + 1;
            TAPB(0, bB); TAPB(1, bA); TAPB(2, bB); TAPB(3, bA); TAPB(4, bB);
            TAPB(5, bA); TAPB(6, bB); TAPB(7, bA); TAPB(8, bB);
            if (chv < 3) {
                __syncthreads();
                STAGE_WRITE(chv + 1);
                __syncthreads();
            }
        }
    }

    // epilogue: plain f32x4 stores of this half's partial (no atomics on s)
    int i = i0 + rw;
    #pragma unroll
    for (int nt = 0; nt < 5; nt++) {
        int o = nt * 16 + l15;
        if (o < O_) {
            #pragma unroll
            for (int m = 0; m < 3; m++) {
                int px = mh * 48 + m * 16 + (lg << 2);
                *(f32x4*)(sOut + ((size_t)(n * O_ + o) * H_ + i) * W_ + px) = acc[m][nt];
            }
        }
    }
    // gap flush: sum the 4 wave slots per channel, one global atomic per channel
    __syncthreads();
    if (t < 128) {
        int chf = t >> 5, cc = t & 31;
        float v = gapP[chf * 128 + cc] + gapP[chf * 128 + 32 + cc]
                + gapP[chf * 128 + 64 + cc] + gapP[chf * 128 + 96 + cc];
        atomicAdd(&gap[n * C_ + kh * 128 + chf * 32 + cc], v);
    }
}

// ---------------- K5: merge partials (s = sA+sB in place) + BN batch stats ----------------
__global__ __launch_bounds__(256) void bnstats_kernel(float* __restrict__ sA,
                                                      const float* __restrict__ sB,
                                                      float* __restrict__ bn_stats) {
    int blk = blockIdx.x;                    // O_*B_ = 576
    int o = blk / B_, nn = blk % B_;
    size_t base = ((size_t)nn * O_ + o) * HW;
    f32x4* pa = (f32x4*)(sA + base);
    const f32x4* pb = (const f32x4*)(sB + base);
    float s1 = 0.f, s2 = 0.f;
    for (int idx = threadIdx.x; idx < HW / 4; idx += 256) {
        f32x4 v = pa[idx] + pb[idx];
        pa[idx] = v;
        s1 += v[0] + v[1] + v[2] + v[3];
        s2 += v[0] * v[0] + v[1] * v[1] + v[2] * v[2] + v[3] * v[3];
    }
    #pragma unroll
    for (int m = 32; m >= 1; m >>= 1) {
        s1 += __shfl_xor(s1, m, 64);
        s2 += __shfl_xor(s2, m, 64);
    }
    __shared__ float r1[4], r2[4];
    int wid = threadIdx.x >> 6;
    if ((threadIdx.x & 63) == 0) { r1[wid] = s1; r2[wid] = s2; }
    __syncthreads();
    if (threadIdx.x == 0) {
        atomicAdd(&bn_stats[o * 2 + 0], r1[0] + r1[1] + r1[2] + r1[3]);
        atomicAdd(&bn_stats[o * 2 + 1], r2[0] + r2[1] + r2[2] + r2[3]);
    }
}

// ---------------- K6: BN + softmax(72) + inline gate + VECTORIZED 9-tap gather ----------------
__global__ __launch_bounds__(256, 2) void out_kernel(const float* __restrict__ x,
                                                     const float* __restrict__ s,
                                                     const float* __restrict__ bn_stats,
                                                     const float* __restrict__ gamma,
                                                     const float* __restrict__ beta,
                                                     const float* __restrict__ xn,
                                                     const float* __restrict__ sstats,
                                                     const float* __restrict__ sw,
                                                     const float* __restrict__ sb,
                                                     float* __restrict__ out) {
    int blk = blockIdx.x;                    // 768
    int n = blk / H_, i = blk % H_;
    int t = threadIdx.x;
    __shared__ float sg[O_][W_];             // exp(bn(s)) for this row
    __shared__ float rden[W_];
    __shared__ float gt[G_][3][100];         // gate at reflected taps; 100-pad -> 400B rows

    int r0 = i - 1; if (r0 < 0) r0 = 1;
    int r2 = i + 1; if (r2 > 95) r2 = 94;
    int rows[3] = { r0, i, r2 };

    for (int idx = t; idx < G_ * 3 * 98; idx += 256) {
        int g = idx / (3 * 98), rem = idx % (3 * 98);
        int r = rem / 98, col = rem % 98;
        int gcol = col - 1;
        if (gcol < 0) gcol = 1; else if (gcol > 95) gcol = 94;
        float v = xn[((size_t)(n * G_ + g)) * HW + rows[r] * W_ + gcol];
        int bg = n * G_ + g;
        float sum = sstats[bg * 2], sumsq = sstats[bg * 2 + 1];
        float mean = sum * (1.f / (float)HW);
        float var = (sumsq - sum * mean) * (1.f / (float)(HW - 1));
        var = fmaxf(var, 0.f);
        float sd = sqrtf(var) + 1e-5f;
        float tv = (v - mean) / sd * sw[g] + sb[g];
        gt[g][r][col] = 1.f / (1.f + expf(-tv));
    }
    const float inv = 1.f / (float)NPX;
    for (int idx = t; idx < O_ * W_; idx += 256) {
        int o = idx / W_, j = idx % W_;
        float sum = bn_stats[o * 2], ssq = bn_stats[o * 2 + 1];
        float mean = sum * inv;
        float var = ssq * inv - mean * mean;
        float sc = rsqrtf(var + 1e-5f) * gamma[o];
        float val = (s[((size_t)(n * O_ + o) * H_ + i) * W_ + j] - mean) * sc + beta[o];
        sg[o][j] = expf(val);
    }
    __syncthreads();
    if (t < W_) {
        float d = 0.f;
        #pragma unroll
        for (int o = 0; o < O_; o++) d += sg[o][t];
        rden[t] = 1.f / d;
    }
    __syncthreads();

    const float* xb = x + (size_t)n * C_ * HW;
    for (int idx = t; idx < C_ * 24; idx += 256) {   // (c, j-quad)
        int c = idx / 24, jq = idx % 24;
        int j0 = jq * 4;
        int g = c >> 5;
        const float* xc = xb + (size_t)c * HW;
        float prod[3][6];
        #pragma unroll
        for (int r = 0; r < 3; r++) {
            const float* xr = xc + rows[r] * W_;
            float4 m = *(const float4*)(xr + j0);
            float lft = (j0 == 0)  ? xr[1]  : xr[j0 - 1];
            float rgt = (j0 == 92) ? xr[94] : xr[j0 + 4];
            const float* gr = &gt[g][r][0];
            float4 gm = *(const float4*)(gr + j0);
            float g4 = gr[j0 + 4], g5 = gr[j0 + 5];
            prod[r][0] = lft * gm.x;
            prod[r][1] = m.x * gm.y;
            prod[r][2] = m.y * gm.z;
            prod[r][3] = m.z * gm.w;
            prod[r][4] = m.w * g4;
            prod[r][5] = rgt * g5;
        }
        float o0 = 0.f, o1 = 0.f, o2 = 0.f, o3 = 0.f;
        #pragma unroll
        for (int r = 0; r < 3; r++)
            #pragma unroll
            for (int dx = 0; dx < 3; dx++) {
                float4 sv = *(const float4*)&sg[g * 9 + r * 3 + dx][j0];
                o0 += prod[r][0 + dx] * sv.x;
                o1 += prod[r][1 + dx] * sv.y;
                o2 += prod[r][2 + dx] * sv.z;
                o3 += prod[r][3 + dx] * sv.w;
            }
        float4 rd = *(const float4*)&rden[j0];
        float4 res;
        res.x = o0 * rd.x; res.y = o1 * rd.y; res.z = o2 * rd.z; res.w = o3 * rd.w;
        *(float4*)(out + ((size_t)(n * C_ + c) * H_ + i) * W_ + j0) = res;
    }
}

extern "C" void kernel_launch(void* const* d_in, const int* in_sizes, int n_in,
                              void* d_out, int out_size, void* d_ws, size_t ws_size,
                              hipStream_t stream) {
    const float* x      = (const float*)d_in[0];
    const float* sge_w  = (const float*)d_in[1];
    const float* sge_b  = (const float*)d_in[2];
    const float* conv_w = (const float*)d_in[3];
    const float* gamma  = (const float*)d_in[4];
    const float* beta   = (const float*)d_in[5];
    float* out = (float*)d_out;
    float* ws = (float*)d_ws;

    // workspace layout (floats)
    float* sge_stats = ws;            // 128    (sum,sumsq per b*g)
    float* bn_stats  = ws + 128;      // 144    (sum,sumsq per o)
    float* gap       = ws + 272;      // 2048   (SUMS, accumulated by conv_kernel)
    float* xng       = ws + 2320;     // 589824 (raw xn; gate computed inline in out)
    unsigned short* bpk = (unsigned short*)(ws + 592144);  // 368640 ushorts
    float* sA        = ws + 776464;   // 5308416 conv partial kh=0, then merged s
    // sB = d_out scratch (21.2MB used of 75.5MB; consumed by bnstats before out_kernel writes)
    float* sB = (float*)d_out;
    // total ws ~24.3 MB

    hipMemsetAsync(d_ws, 0, 2320 * sizeof(float), stream);  // zero stats + gap each call
    hipLaunchKernelGGL(bprep_kernel,   dim3(1440),        dim3(256), 0, stream, conv_w, bpk);
    hipLaunchKernelGGL(conv_kernel,    dim3(768),         dim3(256), 0, stream, x, bpk, sA, sB, gap);
    hipLaunchKernelGGL(xn_kernel,      dim3(B_ * G_ * 36),dim3(256), 0, stream, x, gap, xng, sge_stats);
    hipLaunchKernelGGL(bnstats_kernel, dim3(O_ * B_),     dim3(256), 0, stream, sA, sB, bn_stats);
    hipLaunchKernelGGL(out_kernel,     dim3(B_ * H_),     dim3(256), 0, stream,
                       x, sA, bn_stats, gamma, beta, xng, sge_stats, sge_w, sge_b, out);
}

// Round 14
// 192.654 us; speedup vs baseline: 1.6243x; 1.6243x over previous
//
#include <hip/hip_runtime.h>
#include <hip/hip_bf16.h>

// Problem constants
#define B_  8
#define C_  256
#define H_  96
#define W_  96
#define G_  8
#define CPG 32          // C_/G_
#define KK  9           // 3x3 taps
#define O_  72          // G_*KK conv out channels
#define HW  9216        // H_*W_
#define NPX 73728       // B_*HW (BN population per channel)

typedef short bf16x8 __attribute__((ext_vector_type(8)));
typedef float f32x4 __attribute__((ext_vector_type(4)));

__device__ __forceinline__ unsigned short f2bf(float f) {    // fp32 -> bf16 RNE
    union { float f; unsigned u; } v; v.f = f;
    unsigned r = v.u + 0x7fffu + ((v.u >> 16) & 1u);
    return (unsigned short)(r >> 16);
}
__device__ __forceinline__ float bf2f(unsigned short h) {
    union { float f; unsigned u; } v; v.u = ((unsigned)h) << 16;
    return v.f;
}

// ---------------- K0: weight prepack, per-(tap,chunk) CONTIGUOUS 10KB blocks ----------------
__global__ __launch_bounds__(256) void bprep_kernel(const float* __restrict__ w,
                                                    unsigned short* __restrict__ bpk) {
    int idx = blockIdx.x * 256 + threadIdx.x;        // 72*5120 = 368640
    if (idx >= 368640) return;
    int tix2 = idx / 5120;
    int r = idx - tix2 * 5120;
    int fi = r >> 9;                 // p*5+nt, 0..9
    int p = fi / 5, nt = fi - p * 5;
    int li = r & 511;
    int l = li >> 3, j = li & 7;
    int tap = tix2 >> 3, cblk = tix2 & 7;
    int o = nt * 16 + (l & 15);
    int c = cblk * 32 + ((l >> 4) << 3) + j;
    unsigned short val = 0;
    if (o < O_) {
        float wv = w[((size_t)o * C_ + c) * KK + tap];
        unsigned short h = f2bf(wv);
        val = (p == 0) ? h : f2bf(wv - bf2f(h));
    }
    bpk[idx] = val;
}

// ---------------- K2: xn = sum_ch xg*gapsum, scale 1/HW, + per-(b,g) sum/sumsq ----------------
__global__ __launch_bounds__(256) void xn_kernel(const float* __restrict__ x,
                                                 const float* __restrict__ gap,
                                                 float* __restrict__ xng,
                                                 float* __restrict__ sge_stats) {
    int blk = blockIdx.x;                    // B_*G_*36 = 2304
    int bg = blk / 36, chunk = blk % 36;
    int b = bg >> 3, g = bg & 7;
    int p = chunk * 256 + threadIdx.x;
    const float* xbase = x + ((size_t)b * C_ + g * CPG) * HW + p;
    const float* gp = gap + b * C_ + g * CPG;
    float v = 0.f;
    #pragma unroll
    for (int ch = 0; ch < CPG; ch++) v += xbase[(size_t)ch * HW] * gp[ch];
    v *= (1.f / (float)HW);
    xng[(size_t)bg * HW + p] = v;
    float v1 = v, v2 = v * v;
    #pragma unroll
    for (int m = 32; m >= 1; m >>= 1) {
        v1 += __shfl_xor(v1, m, 64);
        v2 += __shfl_xor(v2, m, 64);
    }
    __shared__ float r1[4], r2[4];
    int wid = threadIdx.x >> 6;
    if ((threadIdx.x & 63) == 0) { r1[wid] = v1; r2[wid] = v2; }
    __syncthreads();
    if (threadIdx.x == 0) {
        atomicAdd(&sge_stats[bg * 2 + 0], r1[0] + r1[1] + r1[2] + r1[3]);
        atomicAdd(&sge_stats[bg * 2 + 1], r2[0] + r2[1] + r2[2] + r2[3]);
    }
}

// ---------------- K4: implicit-GEMM MFMA conv (R12 structure, REVERTED from R13) ----------------
// R13 lesson: launch_bounds(256,2) empirically caps VGPR at 128 on this toolchain
// (R4's (256,1) gave 256) -> 80-reg register B-panels spilled (WRITE 42->147MB).
// B panel through LDS dbuf is the only scheme fitting {128 VGPR, 80KB LDS, 2 blk/CU}.
// Micro-tweak vs R12: B-panel global prefetch issued at TOP of tap body (before
// A-frag LDS reads) -> ~100cy more latency cover before the vmcnt-drained barrier.
#define STAGE_LOAD(CH) do {                                                      \
    const float* p0_ = sb0 + (size_t)(CH) * 32 * HW;                             \
    const float* p1_ = p0_ + HW;                                                 \
    _Pragma("unroll")                                                            \
    for (int m2 = 0; m2 < 6; m2++) {                                             \
        a0[m2] = *(const f32x4*)(p0_ + 4 * m2);                                  \
        a1[m2] = *(const f32x4*)(p1_ + 4 * m2);                                  \
    }                                                                            \
} while (0)

#define PACK_HL(F0, F1, HI, LO) do {                                             \
    unsigned b0_ = __builtin_bit_cast(unsigned, (F0));                           \
    unsigned b1_ = __builtin_bit_cast(unsigned, (F1));                           \
    HI = __builtin_amdgcn_perm(b1_, b0_, 0x07060302u);                           \
    float h0_ = __builtin_bit_cast(float, b0_ & 0xffff0000u);                    \
    float h1_ = __builtin_bit_cast(float, b1_ & 0xffff0000u);                    \
    LO = __builtin_amdgcn_perm(__builtin_bit_cast(unsigned, (F1) - h1_),         \
                               __builtin_bit_cast(unsigned, (F0) - h0_),         \
                               0x07060302u);                                     \
} while (0)

#define STAGE_WRITE(CH) do {                                                     \
    _Pragma("unroll")                                                            \
    for (int m2 = 0; m2 < 6; m2++)                                               \
        _Pragma("unroll")                                                        \
        for (int e = 0; e < 4; e++) {                                            \
            int col = sq * 24 + 1 + m2 * 4 + e;                                  \
            unsigned hi_, lo_;                                                   \
            PACK_HL(a0[m2][e], a1[m2][e], hi_, lo_);                             \
            int row = (rbase + col) ^ par;                                       \
            int off = row * 16 + ((spHi ^ ((col >> 1) & 3)) << 2) + spLo;        \
            xsH[off] = hi_; xsL[off] = lo_;                                      \
        }                                                                        \
    if (sq == 0 || sq == 3) {                                                    \
        float f0_ = (sq == 0) ? a0[0][1] : a0[5][2];                             \
        float f1_ = (sq == 0) ? a1[0][1] : a1[5][2];                             \
        int col = (sq == 0) ? 0 : 97;                                            \
        unsigned hi_, lo_;                                                       \
        PACK_HL(f0_, f1_, hi_, lo_);                                             \
        int row = (rbase + col) ^ par;                                           \
        int off = row * 16 + ((spHi ^ ((col >> 1) & 3)) << 2) + spLo;            \
        xsH[off] = hi_; xsL[off] = lo_;                                          \
    }                                                                            \
    {   /* gap: owned rows srr 1,2 (all lanes run the shuffle) */                \
        float s0_ = 0.f, s1_ = 0.f;                                              \
        if (srr == 1 || srr == 2) {                                              \
            _Pragma("unroll")                                                    \
            for (int m2 = 0; m2 < 6; m2++) {                                     \
                s0_ += a0[m2][0] + a0[m2][1] + a0[m2][2] + a0[m2][3];            \
                s1_ += a1[m2][0] + a1[m2][1] + a1[m2][2] + a1[m2][3];            \
            }                                                                    \
        }                                                                        \
        s0_ += __shfl_xor(s0_, 48, 64);                                          \
        s1_ += __shfl_xor(s1_, 48, 64);                                          \
        if (srr == 1) {                                                          \
            gapP[(CH) * 128 + sq * 32 + 2 * sp]     = s0_;                       \
            gapP[(CH) * 128 + sq * 32 + 2 * sp + 1] = s1_;                       \
        }                                                                        \
    }                                                                            \
} while (0)

__global__ __launch_bounds__(256, 2) void conv_kernel(const float* __restrict__ x,
                                                      const unsigned short* __restrict__ bpk,
                                                      float* __restrict__ sA,
                                                      float* __restrict__ sB,
                                                      float* __restrict__ gap) {
    __shared__ unsigned xsH[4 * 98 * 16];        // 25088 B
    __shared__ unsigned xsL[4 * 98 * 16];        // 25088 B
    __shared__ f32x4 blsv[2][640];               // 20480 B B-panel dbuf (10KB per tap)
    __shared__ float gapP[512];                  // [chunk][wave][cc] single-writer slots
    int phys = blockIdx.x;                       // 768
    int blk = (phys & 7) * 96 + (phys >> 3);     // bijective XCD chunking
    int kh = blk & 1;                            // channel half
    int np = blk >> 1;                           // 0..383
    int n = np / 48, pair = np % 48;
    int i0 = pair * 2;
    int t = threadIdx.x;
    int l = t & 63, wave = t >> 6;
    int rw = wave & 1, mh = wave >> 1;
    int l15 = l & 15, lg = l >> 4;
    int colb = mh * 48 + l15;
    int khb = kh * 4;
    const float* xb = x + (size_t)n * C_ * HW + (size_t)kh * 128 * HW;
    float* sOut = kh ? sB : sA;

    // staging decomposition: sp = ccpair, srr = row, sq = col quarter (== wave)
    int sp = t & 15, srr = (t >> 4) & 3, sq = wave;
    int sri = i0 - 1 + srr;
    if (sri < 0) sri = 1; else if (sri > 95) sri = 94;
    const float* sb0 = xb + (size_t)(2 * sp) * HW + sri * W_ + sq * 24;
    int spHi = sp >> 2, spLo = sp & 3;
    int rbase = srr * 98, par = srr & 1;

    f32x4 acc[3][5];
    #pragma unroll
    for (int m = 0; m < 3; m++)
        #pragma unroll
        for (int nt = 0; nt < 5; nt++)
            #pragma unroll
            for (int e = 0; e < 4; e++) acc[m][nt][e] = 0.f;

    f32x4 a0[6], a1[6];

    // ---- prologue: B(g=0) -> bls[0]; x chunk 0 -> xs ----
    {
        const f32x4* srcB = (const f32x4*)(bpk + (size_t)khb * 5120);
        f32x4 b0 = srcB[t], b1 = srcB[t + 256], b2;
        if (t < 128) b2 = srcB[t + 512];
        blsv[0][t] = b0; blsv[0][t + 256] = b1;
        if (t < 128) blsv[0][t + 512] = b2;
        STAGE_LOAD(0);
        STAGE_WRITE(0);
    }
    __syncthreads();

    for (int ch = 0; ch < 4; ch++) {
        #pragma unroll 1
        for (int tap = 0; tap < 9; tap++) {
            int g = ch * 9 + tap;
            int buf = g & 1;
            int dr = tap / 3, dc = tap - dr * 3;
            // (b) FIRST: issue next tap's B-panel prefetch (max latency cover)
            f32x4 pb0, pb1, pb2;
            bool hasNext = (g < 35);
            if (hasNext) {
                int tix2n = (tap < 8) ? (tap + 1) * 8 + khb + ch : khb + ch + 1;
                const f32x4* srcB = (const f32x4*)(bpk + (size_t)tix2n * 5120);
                pb0 = srcB[t]; pb1 = srcB[t + 256];
                if (t < 128) pb2 = srcB[t + 512];
            }
            // (a) B frags from LDS (linear, conflict-free b128)
            const unsigned short* bb = (const unsigned short*)&blsv[buf][0];
            bf16x8 bh[5], blo[5];
            #pragma unroll
            for (int nt = 0; nt < 5; nt++) {
                bh[nt]  = *(const bf16x8*)(bb + nt * 512 + (l << 3));
                blo[nt] = *(const bf16x8*)(bb + (5 + nt) * 512 + (l << 3));
            }
            // A frags (R8 addressing, test-proven)
            int rr = rw + dr;
            int rpar = rr & 1, rb = rr * 98;
            int cs = ((colb + dc) >> 1) & 3;
            int sl = (lg ^ cs) << 2;
            bf16x8 ah[3], al[3];
            #pragma unroll
            for (int m = 0; m < 3; m++) {
                int row = (rb + colb + m * 16 + dc) ^ rpar;
                ah[m] = *(const bf16x8*)&xsH[row * 16 + sl];
                al[m] = *(const bf16x8*)&xsL[row * 16 + sl];
            }
            // (b2) T14: issue next chunk's x loads at tap 7
            if (tap == 7 && ch < 3) STAGE_LOAD(ch + 1);
            // (c) 45 MFMA
            #pragma unroll
            for (int m = 0; m < 3; m++)
                #pragma unroll
                for (int nt = 0; nt < 5; nt++) {
                    acc[m][nt] = __builtin_amdgcn_mfma_f32_16x16x32_bf16(ah[m], bh[nt],  acc[m][nt], 0, 0, 0);
                    acc[m][nt] = __builtin_amdgcn_mfma_f32_16x16x32_bf16(ah[m], blo[nt], acc[m][nt], 0, 0, 0);
                    acc[m][nt] = __builtin_amdgcn_mfma_f32_16x16x32_bf16(al[m], bh[nt],  acc[m][nt], 0, 0, 0);
                }
            // (d) write next B into other buffer; one barrier per tap
            if (hasNext) {
                blsv[buf ^ 1][t] = pb0; blsv[buf ^ 1][t + 256] = pb1;
                if (t < 128) blsv[buf ^ 1][t + 512] = pb2;
                __syncthreads();
            }
        }
        if (ch < 3) {                            // chunk boundary: xs writes + barrier
            STAGE_WRITE(ch + 1);
            __syncthreads();
        }
    }

    // epilogue: plain f32x4 stores of this half's partial (no atomics on s)
    int i = i0 + rw;
    #pragma unroll
    for (int nt = 0; nt < 5; nt++) {
        int o = nt * 16 + l15;
        if (o < O_) {
            #pragma unroll
            for (int m = 0; m < 3; m++) {
                int px = mh * 48 + m * 16 + (lg << 2);
                *(f32x4*)(sOut + ((size_t)(n * O_ + o) * H_ + i) * W_ + px) = acc[m][nt];
            }
        }
    }
    // gap flush: sum the 4 wave slots per channel, one global atomic per channel
    __syncthreads();
    if (t < 128) {
        int chf = t >> 5, cc = t & 31;
        float v = gapP[chf * 128 + cc] + gapP[chf * 128 + 32 + cc]
                + gapP[chf * 128 + 64 + cc] + gapP[chf * 128 + 96 + cc];
        atomicAdd(&gap[n * C_ + kh * 128 + chf * 32 + cc], v);
    }
}

// ---------------- K5: merge partials (s = sA+sB in place) + BN batch stats ----------------
__global__ __launch_bounds__(256) void bnstats_kernel(float* __restrict__ sA,
                                                      const float* __restrict__ sB,
                                                      float* __restrict__ bn_stats) {
    int blk = blockIdx.x;                    // O_*B_ = 576
    int o = blk / B_, nn = blk % B_;
    size_t base = ((size_t)nn * O_ + o) * HW;
    f32x4* pa = (f32x4*)(sA + base);
    const f32x4* pb = (const f32x4*)(sB + base);
    float s1 = 0.f, s2 = 0.f;
    for (int idx = threadIdx.x; idx < HW / 4; idx += 256) {
        f32x4 v = pa[idx] + pb[idx];
        pa[idx] = v;
        s1 += v[0] + v[1] + v[2] + v[3];
        s2 += v[0] * v[0] + v[1] * v[1] + v[2] * v[2] + v[3] * v[3];
    }
    #pragma unroll
    for (int m = 32; m >= 1; m >>= 1) {
        s1 += __shfl_xor(s1, m, 64);
        s2 += __shfl_xor(s2, m, 64);
    }
    __shared__ float r1[4], r2[4];
    int wid = threadIdx.x >> 6;
    if ((threadIdx.x & 63) == 0) { r1[wid] = s1; r2[wid] = s2; }
    __syncthreads();
    if (threadIdx.x == 0) {
        atomicAdd(&bn_stats[o * 2 + 0], r1[0] + r1[1] + r1[2] + r1[3]);
        atomicAdd(&bn_stats[o * 2 + 1], r2[0] + r2[1] + r2[2] + r2[3]);
    }
}

// ---------------- K6: BN + softmax(72) + inline gate + VECTORIZED 9-tap gather ----------------
__global__ __launch_bounds__(256, 2) void out_kernel(const float* __restrict__ x,
                                                     const float* __restrict__ s,
                                                     const float* __restrict__ bn_stats,
                                                     const float* __restrict__ gamma,
                                                     const float* __restrict__ beta,
                                                     const float* __restrict__ xn,
                                                     const float* __restrict__ sstats,
                                                     const float* __restrict__ sw,
                                                     const float* __restrict__ sb,
                                                     float* __restrict__ out) {
    int blk = blockIdx.x;                    // 768
    int n = blk / H_, i = blk % H_;
    int t = threadIdx.x;
    __shared__ float sg[O_][W_];             // exp(bn(s)) for this row
    __shared__ float rden[W_];
    __shared__ float gt[G_][3][100];         // gate at reflected taps; 100-pad -> 400B rows

    int r0 = i - 1; if (r0 < 0) r0 = 1;
    int r2 = i + 1; if (r2 > 95) r2 = 94;
    int rows[3] = { r0, i, r2 };

    for (int idx = t; idx < G_ * 3 * 98; idx += 256) {
        int g = idx / (3 * 98), rem = idx % (3 * 98);
        int r = rem / 98, col = rem % 98;
        int gcol = col - 1;
        if (gcol < 0) gcol = 1; else if (gcol > 95) gcol = 94;
        float v = xn[((size_t)(n * G_ + g)) * HW + rows[r] * W_ + gcol];
        int bg = n * G_ + g;
        float sum = sstats[bg * 2], sumsq = sstats[bg * 2 + 1];
        float mean = sum * (1.f / (float)HW);
        float var = (sumsq - sum * mean) * (1.f / (float)(HW - 1));
        var = fmaxf(var, 0.f);
        float sd = sqrtf(var) + 1e-5f;
        float tv = (v - mean) / sd * sw[g] + sb[g];
        gt[g][r][col] = 1.f / (1.f + expf(-tv));
    }
    const float inv = 1.f / (float)NPX;
    for (int idx = t; idx < O_ * W_; idx += 256) {
        int o = idx / W_, j = idx % W_;
        float sum = bn_stats[o * 2], ssq = bn_stats[o * 2 + 1];
        float mean = sum * inv;
        float var = ssq * inv - mean * mean;
        float sc = rsqrtf(var + 1e-5f) * gamma[o];
        float val = (s[((size_t)(n * O_ + o) * H_ + i) * W_ + j] - mean) * sc + beta[o];
        sg[o][j] = expf(val);
    }
    __syncthreads();
    if (t < W_) {
        float d = 0.f;
        #pragma unroll
        for (int o = 0; o < O_; o++) d += sg[o][t];
        rden[t] = 1.f / d;
    }
    __syncthreads();

    const float* xb = x + (size_t)n * C_ * HW;
    for (int idx = t; idx < C_ * 24; idx += 256) {   // (c, j-quad)
        int c = idx / 24, jq = idx % 24;
        int j0 = jq * 4;
        int g = c >> 5;
        const float* xc = xb + (size_t)c * HW;
        float prod[3][6];
        #pragma unroll
        for (int r = 0; r < 3; r++) {
            const float* xr = xc + rows[r] * W_;
            float4 m = *(const float4*)(xr + j0);
            float lft = (j0 == 0)  ? xr[1]  : xr[j0 - 1];
            float rgt = (j0 == 92) ? xr[94] : xr[j0 + 4];
            const float* gr = &gt[g][r][0];
            float4 gm = *(const float4*)(gr + j0);
            float g4 = gr[j0 + 4], g5 = gr[j0 + 5];
            prod[r][0] = lft * gm.x;
            prod[r][1] = m.x * gm.y;
            prod[r][2] = m.y * gm.z;
            prod[r][3] = m.z * gm.w;
            prod[r][4] = m.w * g4;
            prod[r][5] = rgt * g5;
        }
        float o0 = 0.f, o1 = 0.f, o2 = 0.f, o3 = 0.f;
        #pragma unroll
        for (int r = 0; r < 3; r++)
            #pragma unroll
            for (int dx = 0; dx < 3; dx++) {
                float4 sv = *(const float4*)&sg[g * 9 + r * 3 + dx][j0];
                o0 += prod[r][0 + dx] * sv.x;
                o1 += prod[r][1 + dx] * sv.y;
                o2 += prod[r][2 + dx] * sv.z;
                o3 += prod[r][3 + dx] * sv.w;
            }
        float4 rd = *(const float4*)&rden[j0];
        float4 res;
        res.x = o0 * rd.x; res.y = o1 * rd.y; res.z = o2 * rd.z; res.w = o3 * rd.w;
        *(float4*)(out + ((size_t)(n * C_ + c) * H_ + i) * W_ + j0) = res;
    }
}

extern "C" void kernel_launch(void* const* d_in, const int* in_sizes, int n_in,
                              void* d_out, int out_size, void* d_ws, size_t ws_size,
                              hipStream_t stream) {
    const float* x      = (const float*)d_in[0];
    const float* sge_w  = (const float*)d_in[1];
    const float* sge_b  = (const float*)d_in[2];
    const float* conv_w = (const float*)d_in[3];
    const float* gamma  = (const float*)d_in[4];
    const float* beta   = (const float*)d_in[5];
    float* out = (float*)d_out;
    float* ws = (float*)d_ws;

    // workspace layout (floats)
    float* sge_stats = ws;            // 128    (sum,sumsq per b*g)
    float* bn_stats  = ws + 128;      // 144    (sum,sumsq per o)
    float* gap       = ws + 272;      // 2048   (SUMS, accumulated by conv_kernel)
    float* xng       = ws + 2320;     // 589824 (raw xn; gate computed inline in out)
    unsigned short* bpk = (unsigned short*)(ws + 592144);  // 368640 ushorts
    float* sA        = ws + 776464;   // 5308416 conv partial kh=0, then merged s
    // sB = d_out scratch (21.2MB used of 75.5MB; consumed by bnstats before out_kernel writes)
    float* sB = (float*)d_out;
    // total ws ~24.3 MB

    hipMemsetAsync(d_ws, 0, 2320 * sizeof(float), stream);  // zero stats + gap each call
    hipLaunchKernelGGL(bprep_kernel,   dim3(1440),        dim3(256), 0, stream, conv_w, bpk);
    hipLaunchKernelGGL(conv_kernel,    dim3(768),         dim3(256), 0, stream, x, bpk, sA, sB, gap);
    hipLaunchKernelGGL(xn_kernel,      dim3(B_ * G_ * 36),dim3(256), 0, stream, x, gap, xng, sge_stats);
    hipLaunchKernelGGL(bnstats_kernel, dim3(O_ * B_),     dim3(256), 0, stream, sA, sB, bn_stats);
    hipLaunchKernelGGL(out_kernel,     dim3(B_ * H_),     dim3(256), 0, stream,
                       x, sA, bn_stats, gamma, beta, xng, sge_stats, sge_w, sge_b, out);
}